// Round 6
// baseline (342.625 us; speedup 1.0000x reference)
//
#include <hip/hip_runtime.h>

#define NB 8
#define NC 128
#define NM 4096

typedef __attribute__((ext_vector_type(8))) short short8;
typedef __attribute__((ext_vector_type(4))) float floatx4;

#define MFMA(a, b, c) __builtin_amdgcn_mfma_f32_16x16x32_bf16(a, b, c, 0, 0, 0)
#define EXP2F(x) __builtin_amdgcn_exp2f(x)

union S8U { short8 v; uint2 u2[2]; };

__device__ __forceinline__ unsigned pack2bf(float a, float b) {
    unsigned ua = __float_as_uint(a);
    unsigned ub = __float_as_uint(b);
    ua += 0x7fffu + ((ua >> 16) & 1u);
    ub += 0x7fffu + ((ub >> 16) & 1u);
    return (ua >> 16) | (ub & 0xffff0000u);
}

__device__ __forceinline__ void fma4(float4& a, float s, const float4& v) {
    a.x += s * v.x; a.y += s * v.y; a.z += s * v.z; a.w += s * v.w;
}

// ---------------------------------------------------------------------------
// P1: fT[b][m][c] = bf16( f[b][c][m] * sqrt(C^-1/2 * log2e) )
// ---------------------------------------------------------------------------
__global__ __launch_bounds__(256) void prep_ft(
    const float* __restrict__ f, unsigned short* __restrict__ fT)
{
    __shared__ float Ls[128][65];
    const int tid = threadIdx.x;
    const int b   = blockIdx.x & 7;
    const int m0  = (blockIdx.x >> 3) << 6;
    const float* fb = f + (size_t)b * NC * NM;
    #pragma unroll
    for (int k = 0; k < 32; ++k) {
        int idx = tid + (k << 8);
        int c = idx >> 6, mm = idx & 63;
        Ls[c][mm] = fb[(size_t)c * NM + m0 + mm];
    }
    __syncthreads();
    const float SQ = 0.35712442f;   // sqrt(2^-3.5 * log2(e))
    const int m  = tid >> 2;
    const int ch = (tid & 3) << 5;
    unsigned pk[16];
    #pragma unroll
    for (int i = 0; i < 16; ++i)
        pk[i] = pack2bf(Ls[ch + 2 * i][m] * SQ, Ls[ch + 2 * i + 1][m] * SQ);
    unsigned short* dst = fT + ((size_t)b * NM + m0 + m) * NC + ch;
    #pragma unroll
    for (int i = 0; i < 4; ++i)
        ((uint4*)dst)[i] = make_uint4(pk[4 * i], pk[4 * i + 1], pk[4 * i + 2], pk[4 * i + 3]);
}

// ---------------------------------------------------------------------------
// P2: gN[b][o][n] = bf16( sum_c w1[o,c] f[b,c,n] ), o in [0,128)
// grid 256 = b(8) x nt(4) x oc(8); 256 thr, 4 n x 16 o each.
// ---------------------------------------------------------------------------
__global__ __launch_bounds__(256) void prep_g(
    const float* __restrict__ f, const float* __restrict__ w1,
    unsigned short* __restrict__ gN)
{
    __shared__ float Ws[128][16];
    const int tid = threadIdx.x;
    const int b   = blockIdx.x & 7;
    const int nt  = (blockIdx.x >> 3) & 3;
    const int oc  = blockIdx.x >> 5;         // 0..7
    const int n0  = nt << 10;
    const int o0  = oc << 4;
    for (int i = tid; i < 128 * 16; i += 256) {
        int c = i >> 4, k = i & 15;
        Ws[c][k] = w1[(o0 + k) * 256 + c];
    }
    __syncthreads();

    const float* fb = f + (size_t)b * NC * NM + n0 + (tid << 2);
    float4 acc[16];
    #pragma unroll
    for (int j = 0; j < 16; ++j) acc[j] = make_float4(0.f, 0.f, 0.f, 0.f);

    for (int c = 0; c < NC; ++c) {
        float4 fv = *(const float4*)(fb + (size_t)c * NM);
        const float4* wq = (const float4*)&Ws[c][0];
        float4 w0 = wq[0], w1q = wq[1], w2q = wq[2], w3q = wq[3];
        fma4(acc[0],  w0.x,  fv); fma4(acc[1],  w0.y,  fv);
        fma4(acc[2],  w0.z,  fv); fma4(acc[3],  w0.w,  fv);
        fma4(acc[4],  w1q.x, fv); fma4(acc[5],  w1q.y, fv);
        fma4(acc[6],  w1q.z, fv); fma4(acc[7],  w1q.w, fv);
        fma4(acc[8],  w2q.x, fv); fma4(acc[9],  w2q.y, fv);
        fma4(acc[10], w2q.z, fv); fma4(acc[11], w2q.w, fv);
        fma4(acc[12], w3q.x, fv); fma4(acc[13], w3q.y, fv);
        fma4(acc[14], w3q.z, fv); fma4(acc[15], w3q.w, fv);
    }

    #pragma unroll
    for (int j = 0; j < 16; ++j) {
        unsigned lo = pack2bf(acc[j].x, acc[j].y);
        unsigned hi = pack2bf(acc[j].z, acc[j].w);
        *(uint2*)(gN + ((size_t)b * NC + o0 + j) * NM + n0 + (tid << 2)) =
            make_uint2(lo, hi);
    }
}

// ---------------------------------------------------------------------------
// Main: MFMA flash attention + fused cls head (h computed in-kernel).
// grid 1024 = b(8 low bits) x mblock(128, 32 m each); 256 thr = 4 waves.
// Per iter (TN=64): wave w computes S^T for n-local w*16..w*16+15, all 32 m,
// writes bf16 P to LDS (double-buffered, 1 barrier), then all waves read the
// full 64-n P rows as A-frags: u += P*G (wave's own 32 o), l += P*ones.
// Skip path h = fT * (w1b/SQ) via 16 MFMAs after the loop — same C/D layout
// as u, so the epilogue needs no hT array at all.
// ---------------------------------------------------------------------------
__global__ __launch_bounds__(256, 3) void attn_kernel(
    const unsigned short* __restrict__ fT,
    const unsigned short* __restrict__ gN,
    const float* __restrict__ w1,
    const float* __restrict__ b1v, const float* __restrict__ gammav,
    const float* __restrict__ betav, const float* __restrict__ rmeanv,
    const float* __restrict__ rvarv, const float* __restrict__ w2v,
    const float* __restrict__ b2v, float* __restrict__ out)
{
    __shared__ unsigned short Ps[2][32][72];   // [buf][m][n] bf16 P-hat
    __shared__ float opart[4][32];

    const int tid = threadIdx.x;
    const int w   = tid >> 6;
    const int l   = tid & 63;
    const int lm  = l & 15;
    const int lq  = l >> 4;
    const int b   = blockIdx.x & 7;
    const int m0  = (blockIdx.x >> 3) << 5;

    const unsigned short* fTb = fT + (size_t)b * NM * NC;
    const unsigned short* gNb = gN + (size_t)b * NC * NM;

    // stationary Q frags: qf[mt][ks] covers m = m0+mt*16+lm, c = ks*32+lq*8
    short8 qf[2][4];
    {
        const unsigned short* qp = fTb + (size_t)(m0 + lm) * NC + lq * 8;
        #pragma unroll
        for (int mt = 0; mt < 2; ++mt)
            #pragma unroll
            for (int ks = 0; ks < 4; ++ks)
                qf[mt][ks] = *(const short8*)(qp + mt * 16 * NC + ks * 32);
    }

    short8 ones;
    #pragma unroll
    for (int j = 0; j < 8; ++j) ones[j] = (short)0x3F80;   // bf16 1.0

    // K rows: n = it*64 + w*16 + lm
    const unsigned short* kp = fTb + (size_t)(w * 16 + lm) * NC + lq * 8;
    // G rows: o = w*32 + j*16 + lm ; cols n = it*64 + k2*32 + lq*8
    const unsigned short* gpa = gNb + (size_t)(w * 32 + lm) * NM + lq * 8;
    const unsigned short* gpb = gpa + (size_t)16 * NM;

    short8 kf[4], gfa[2], gfb[2];
    #pragma unroll
    for (int ks = 0; ks < 4; ++ks) kf[ks] = *(const short8*)(kp + ks * 32);
    #pragma unroll
    for (int k2 = 0; k2 < 2; ++k2) {
        gfa[k2] = *(const short8*)(gpa + k2 * 32);
        gfb[k2] = *(const short8*)(gpb + k2 * 32);
    }

    floatx4 u[2][2], lones[2];
    #pragma unroll
    for (int mt = 0; mt < 2; ++mt) {
        u[mt][0] = (floatx4){0.f, 0.f, 0.f, 0.f};
        u[mt][1] = (floatx4){0.f, 0.f, 0.f, 0.f};
        lones[mt] = (floatx4){0.f, 0.f, 0.f, 0.f};
    }

    for (int it = 0; it < 64; ++it) {
        const int buf = it & 1;

        // ---- S^T = K * Q^T (16 n x 32 m per wave), acc seeded -24 ----
        floatx4 sv[2];
        #pragma unroll
        for (int mt = 0; mt < 2; ++mt) {
            floatx4 a = {-24.f, -24.f, -24.f, -24.f};
            #pragma unroll
            for (int ks = 0; ks < 4; ++ks)
                a = MFMA(kf[ks], qf[mt][ks], a);
            sv[mt] = a;
        }
        // prefetch next K
        {
            const int kstep = (it < 63) ? 64 * NC : 0;
            kp += kstep;
            #pragma unroll
            for (int ks = 0; ks < 4; ++ks) kf[ks] = *(const short8*)(kp + ks * 32);
        }

        // ---- p-hat = bf16(exp2(s)) -> LDS P tile ----
        #pragma unroll
        for (int mt = 0; mt < 2; ++mt) {
            float p0 = EXP2F(sv[mt][0]);
            float p1 = EXP2F(sv[mt][1]);
            float p2 = EXP2F(sv[mt][2]);
            float p3 = EXP2F(sv[mt][3]);
            *(uint2*)&Ps[buf][mt * 16 + lm][w * 16 + lq * 4] =
                make_uint2(pack2bf(p0, p1), pack2bf(p2, p3));
        }
        __syncthreads();

        // ---- PV + l over the full 64-n tile ----
        #pragma unroll
        for (int k2 = 0; k2 < 2; ++k2) {
            short8 pf[2];
            #pragma unroll
            for (int mt = 0; mt < 2; ++mt)
                pf[mt] = *(const short8*)&Ps[buf][mt * 16 + lm][k2 * 32 + lq * 8];
            #pragma unroll
            for (int mt = 0; mt < 2; ++mt) {
                u[mt][0]  = MFMA(pf[mt], gfa[k2], u[mt][0]);
                u[mt][1]  = MFMA(pf[mt], gfb[k2], u[mt][1]);
                lones[mt] = MFMA(pf[mt], ones,    lones[mt]);
            }
        }
        // prefetch next G
        {
            const int gstep = (it < 63) ? 64 : 0;
            gpa += gstep; gpb += gstep;
            #pragma unroll
            for (int k2 = 0; k2 < 2; ++k2) {
                gfa[k2] = *(const short8*)(gpa + k2 * 32);
                gfb[k2] = *(const short8*)(gpb + k2 * 32);
            }
        }
    }

    // ---- skip path h = fT * (w1b / SQ): same C/D layout as u ----
    floatx4 hacc[2][2];
    {
        const float RSQ = 2.8001530f;   // 1 / 0.35712442
        #pragma unroll
        for (int j = 0; j < 2; ++j) {
            int o = w * 32 + j * 16 + lm;
            short8 wf[4];
            #pragma unroll
            for (int ks = 0; ks < 4; ++ks) {
                const float* wp = w1 + (size_t)o * 256 + NC + ks * 32 + lq * 8;
                S8U t;
                t.u2[0] = make_uint2(pack2bf(wp[0] * RSQ, wp[1] * RSQ),
                                     pack2bf(wp[2] * RSQ, wp[3] * RSQ));
                t.u2[1] = make_uint2(pack2bf(wp[4] * RSQ, wp[5] * RSQ),
                                     pack2bf(wp[6] * RSQ, wp[7] * RSQ));
                wf[ks] = t.v;
            }
            #pragma unroll
            for (int mt = 0; mt < 2; ++mt) {
                floatx4 a = {0.f, 0.f, 0.f, 0.f};
                #pragma unroll
                for (int ks = 0; ks < 4; ++ks)
                    a = MFMA(qf[mt][ks], wf[ks], a);
                hacc[mt][j] = a;
            }
        }
    }

    // ---- epilogue: BN + leaky + w2 dot over this wave's 32 o ----
    float Abn[2], Dbn[2], W2[2];
    #pragma unroll
    for (int j = 0; j < 2; ++j) {
        int o = w * 32 + j * 16 + lm;
        float Ar = gammav[o] * rsqrtf(rvarv[o] + 1e-5f);
        Abn[j] = Ar;
        Dbn[j] = (b1v[o] - rmeanv[o]) * Ar + betav[o];
        W2[j]  = w2v[o];
    }
    float av[8];
    #pragma unroll
    for (int mt = 0; mt < 2; ++mt) {
        #pragma unroll
        for (int r = 0; r < 4; ++r) {
            float rl = 1.f / lones[mt][r];
            float t0 = Abn[0] * (u[mt][0][r] * rl + hacc[mt][0][r]) + Dbn[0];
            float t1 = Abn[1] * (u[mt][1][r] * rl + hacc[mt][1][r]) + Dbn[1];
            t0 = t0 >= 0.f ? t0 : 0.01f * t0;
            t1 = t1 >= 0.f ? t1 : 0.01f * t1;
            av[mt * 4 + r] = W2[0] * t0 + W2[1] * t1;
        }
    }
    #pragma unroll
    for (int i = 0; i < 8; ++i) {
        av[i] += __shfl_xor(av[i], 1);
        av[i] += __shfl_xor(av[i], 2);
        av[i] += __shfl_xor(av[i], 4);
        av[i] += __shfl_xor(av[i], 8);
    }
    __syncthreads();   // Ps reads done; reuse nothing, just order opart
    if (lm == 0) {
        #pragma unroll
        for (int mt = 0; mt < 2; ++mt)
            #pragma unroll
            for (int r = 0; r < 4; ++r)
                opart[w][mt * 16 + lq * 4 + r] = av[mt * 4 + r];
    }
    __syncthreads();
    if (tid < 32)
        out[(size_t)b * NM + m0 + tid] =
            b2v[0] + opart[0][tid] + opart[1][tid] + opart[2][tid] + opart[3][tid];
}

extern "C" void kernel_launch(void* const* d_in, const int* in_sizes, int n_in,
                              void* d_out, int out_size, void* d_ws, size_t ws_size,
                              hipStream_t stream) {
    const float* f     = (const float*)d_in[0];
    const float* w1    = (const float*)d_in[1];
    const float* b1    = (const float*)d_in[2];
    const float* gamma = (const float*)d_in[3];
    const float* beta  = (const float*)d_in[4];
    const float* rmean = (const float*)d_in[5];
    const float* rvar  = (const float*)d_in[6];
    const float* w2    = (const float*)d_in[7];
    const float* b2    = (const float*)d_in[8];
    float* out = (float*)d_out;

    unsigned short* fT = (unsigned short*)d_ws;              // 8 MB bf16 [b][m][c]
    unsigned short* gN = fT + (size_t)NB * NM * NC;          // 8 MB bf16 [b][o][n]

    hipLaunchKernelGGL(prep_ft, dim3(512), dim3(256), 0, stream, f, fT);
    hipLaunchKernelGGL(prep_g,  dim3(256), dim3(256), 0, stream, f, w1, gN);
    hipLaunchKernelGGL(attn_kernel, dim3(1024), dim3(256), 0, stream,
                       fT, gN, w1, b1, gamma, beta, rmean, rvar, w2, b2, out);
}

// Round 9
// 224.275 us; speedup vs baseline: 1.5277x; 1.5277x over previous
//
#include <hip/hip_runtime.h>

#define NB 8
#define NC 128
#define NM 4096

typedef __attribute__((ext_vector_type(8))) short short8;
typedef __attribute__((ext_vector_type(4))) float floatx4;

#define MFMA(a, b, c) __builtin_amdgcn_mfma_f32_16x16x32_bf16(a, b, c, 0, 0, 0)
#define EXP2F(x) __builtin_amdgcn_exp2f(x)

union S8U { short8 v; uint2 u2[2]; };

__device__ __forceinline__ unsigned pack2bf(float a, float b) {
    unsigned ua = __float_as_uint(a);
    unsigned ub = __float_as_uint(b);
    ua += 0x7fffu + ((ua >> 16) & 1u);
    ub += 0x7fffu + ((ub >> 16) & 1u);
    return (ua >> 16) | (ub & 0xffff0000u);
}

__device__ __forceinline__ void fma4(float4& a, float s, const float4& v) {
    a.x += s * v.x; a.y += s * v.y; a.z += s * v.z; a.w += s * v.w;
}

// ---------------------------------------------------------------------------
// P1: fT[b][m][c] = bf16( f[b][c][m] * sqrt(C^-1/2 * log2e) )
// ---------------------------------------------------------------------------
__global__ __launch_bounds__(256) void prep_ft(
    const float* __restrict__ f, unsigned short* __restrict__ fT)
{
    __shared__ float Ls[128][65];
    const int tid = threadIdx.x;
    const int b   = blockIdx.x & 7;
    const int m0  = (blockIdx.x >> 3) << 6;
    const float* fb = f + (size_t)b * NC * NM;
    #pragma unroll
    for (int k = 0; k < 32; ++k) {
        int idx = tid + (k << 8);
        int c = idx >> 6, mm = idx & 63;
        Ls[c][mm] = fb[(size_t)c * NM + m0 + mm];
    }
    __syncthreads();
    const float SQ = 0.35712442f;   // sqrt(2^-3.5 * log2(e))
    const int m  = tid >> 2;
    const int ch = (tid & 3) << 5;
    unsigned pk[16];
    #pragma unroll
    for (int i = 0; i < 16; ++i)
        pk[i] = pack2bf(Ls[ch + 2 * i][m] * SQ, Ls[ch + 2 * i + 1][m] * SQ);
    unsigned short* dst = fT + ((size_t)b * NM + m0 + m) * NC + ch;
    #pragma unroll
    for (int i = 0; i < 4; ++i)
        ((uint4*)dst)[i] = make_uint4(pk[4 * i], pk[4 * i + 1], pk[4 * i + 2], pk[4 * i + 3]);
}

// ---------------------------------------------------------------------------
// P2: gN[b][o][n] = bf16( sum_c w1[o,c] f[b,c,n] ), o in [0,128)
// grid 512 = b(8) x nt(4) x oc(16); 256 thr, 4 n x 8 o each.
// ---------------------------------------------------------------------------
__global__ __launch_bounds__(256) void prep_g(
    const float* __restrict__ f, const float* __restrict__ w1,
    unsigned short* __restrict__ gN)
{
    __shared__ float Ws[128][8];
    const int tid = threadIdx.x;
    const int b   = blockIdx.x & 7;
    const int nt  = (blockIdx.x >> 3) & 3;
    const int oc  = blockIdx.x >> 5;         // 0..15
    const int n0  = nt << 10;
    const int o0  = oc << 3;
    for (int i = tid; i < 128 * 8; i += 256) {
        int c = i >> 3, k = i & 7;
        Ws[c][k] = w1[(o0 + k) * 256 + c];
    }
    __syncthreads();

    const float* fb = f + (size_t)b * NC * NM + n0 + (tid << 2);
    float4 acc[8];
    #pragma unroll
    for (int j = 0; j < 8; ++j) acc[j] = make_float4(0.f, 0.f, 0.f, 0.f);

    for (int c = 0; c < NC; ++c) {
        float4 fv = *(const float4*)(fb + (size_t)c * NM);
        const float4* wq = (const float4*)&Ws[c][0];
        float4 w0 = wq[0], w1q = wq[1];
        fma4(acc[0], w0.x,  fv); fma4(acc[1], w0.y,  fv);
        fma4(acc[2], w0.z,  fv); fma4(acc[3], w0.w,  fv);
        fma4(acc[4], w1q.x, fv); fma4(acc[5], w1q.y, fv);
        fma4(acc[6], w1q.z, fv); fma4(acc[7], w1q.w, fv);
    }

    #pragma unroll
    for (int j = 0; j < 8; ++j) {
        unsigned lo = pack2bf(acc[j].x, acc[j].y);
        unsigned hi = pack2bf(acc[j].z, acc[j].w);
        *(uint2*)(gN + ((size_t)b * NC + o0 + j) * NM + n0 + (tid << 2)) =
            make_uint2(lo, hi);
    }
}

// ---------------------------------------------------------------------------
// Main: MFMA flash attention + fused cls head, TN=128 per iteration.
// grid 512 = b(8) x mblock(64, 64 m); 256 thr = 4 waves, 2 blocks/CU.
// Per iter: wave w computes S^T for n-locals {w*16..+15} and {64+w*16..+15}
// (dual K tiles, R5 pattern), writes bf16 P to Ps[64][128] (double-buffered,
// 1 barrier/iter — R4 pattern), then PV over k2<4 with the wave's 32 o.
// l via ones-B MFMA on the same P A-frags (R4).  h = fT*(w1b/SQ) in-kernel
// via MFMA (R6).  32 iterations instead of 64 -> half the latency periods.
// ---------------------------------------------------------------------------
__global__ __launch_bounds__(256, 2) void attn_kernel(
    const unsigned short* __restrict__ fT,
    const unsigned short* __restrict__ gN,
    const float* __restrict__ w1,
    const float* __restrict__ b1v, const float* __restrict__ gammav,
    const float* __restrict__ betav, const float* __restrict__ rmeanv,
    const float* __restrict__ rvarv, const float* __restrict__ w2v,
    const float* __restrict__ b2v, float* __restrict__ out)
{
    __shared__ unsigned short Ps[2][64][136];   // [buf][m][n] bf16 P-hat
    __shared__ float opart[4][64];

    const int tid = threadIdx.x;
    const int w   = tid >> 6;
    const int l   = tid & 63;
    const int lm  = l & 15;
    const int lq  = l >> 4;
    const int b   = blockIdx.x & 7;
    const int m0  = (blockIdx.x >> 3) << 6;

    const unsigned short* fTb = fT + (size_t)b * NM * NC;
    const unsigned short* gNb = gN + (size_t)b * NC * NM;

    // stationary Q frags: qf[mt][ks] covers m = m0+mt*16+lm, c = ks*32+lq*8
    short8 qf[4][4];
    {
        const unsigned short* qp = fTb + (size_t)(m0 + lm) * NC + lq * 8;
        #pragma unroll
        for (int mt = 0; mt < 4; ++mt)
            #pragma unroll
            for (int ks = 0; ks < 4; ++ks)
                qf[mt][ks] = *(const short8*)(qp + mt * 16 * NC + ks * 32);
    }

    short8 ones;
    #pragma unroll
    for (int j = 0; j < 8; ++j) ones[j] = (short)0x3F80;   // bf16 1.0

    // K rows: nA = it*128 + w*16 + lm ; nB = nA + 64
    const unsigned short* kpA = fTb + (size_t)(w * 16 + lm) * NC + lq * 8;
    const unsigned short* kpB = kpA + (size_t)64 * NC;
    // G rows: o = w*32 + {lm | 16+lm}; cols n = it*128 + k2*32 + lq*8
    const unsigned short* gp0 = gNb + (size_t)(w * 32 + lm) * NM + lq * 8;
    const unsigned short* gp1 = gp0 + (size_t)16 * NM;

    short8 kfA[4], kfB[4], gf0[4], gf1[4];
    #pragma unroll
    for (int ks = 0; ks < 4; ++ks) {
        kfA[ks] = *(const short8*)(kpA + ks * 32);
        kfB[ks] = *(const short8*)(kpB + ks * 32);
    }
    #pragma unroll
    for (int k2 = 0; k2 < 4; ++k2) {
        gf0[k2] = *(const short8*)(gp0 + k2 * 32);
        gf1[k2] = *(const short8*)(gp1 + k2 * 32);
    }

    floatx4 u[4][2], lones[4];
    #pragma unroll
    for (int mt = 0; mt < 4; ++mt) {
        u[mt][0] = (floatx4){0.f, 0.f, 0.f, 0.f};
        u[mt][1] = (floatx4){0.f, 0.f, 0.f, 0.f};
        lones[mt] = (floatx4){0.f, 0.f, 0.f, 0.f};
    }

    for (int it = 0; it < 32; ++it) {
        const int buf = it & 1;

        // ---- S^T = K * Q^T (two 16-n tiles), acc seeded -24 ----
        floatx4 svA[4], svB[4];
        #pragma unroll
        for (int mt = 0; mt < 4; ++mt) {
            floatx4 a = {-24.f, -24.f, -24.f, -24.f};
            floatx4 bb = {-24.f, -24.f, -24.f, -24.f};
            #pragma unroll
            for (int ks = 0; ks < 4; ++ks) {
                a  = MFMA(kfA[ks], qf[mt][ks], a);
                bb = MFMA(kfB[ks], qf[mt][ks], bb);
            }
            svA[mt] = a; svB[mt] = bb;
        }
        // prefetch next K
        {
            const int kstep = (it < 31) ? 128 * NC : 0;
            kpA += kstep; kpB += kstep;
            #pragma unroll
            for (int ks = 0; ks < 4; ++ks) {
                kfA[ks] = *(const short8*)(kpA + ks * 32);
                kfB[ks] = *(const short8*)(kpB + ks * 32);
            }
        }

        // ---- p-hat = bf16(exp2(s)) -> LDS P tile ----
        #pragma unroll
        for (int mt = 0; mt < 4; ++mt) {
            *(uint2*)&Ps[buf][mt * 16 + lm][w * 16 + lq * 4] =
                make_uint2(pack2bf(EXP2F(svA[mt][0]), EXP2F(svA[mt][1])),
                           pack2bf(EXP2F(svA[mt][2]), EXP2F(svA[mt][3])));
            *(uint2*)&Ps[buf][mt * 16 + lm][64 + w * 16 + lq * 4] =
                make_uint2(pack2bf(EXP2F(svB[mt][0]), EXP2F(svB[mt][1])),
                           pack2bf(EXP2F(svB[mt][2]), EXP2F(svB[mt][3])));
        }
        __syncthreads();

        // ---- PV + l over the 128-n tile ----
        #pragma unroll
        for (int k2 = 0; k2 < 4; ++k2) {
            short8 pf[4];
            #pragma unroll
            for (int mt = 0; mt < 4; ++mt)
                pf[mt] = *(const short8*)&Ps[buf][mt * 16 + lm][k2 * 32 + lq * 8];
            #pragma unroll
            for (int mt = 0; mt < 4; ++mt) {
                u[mt][0]  = MFMA(pf[mt], gf0[k2], u[mt][0]);
                u[mt][1]  = MFMA(pf[mt], gf1[k2], u[mt][1]);
                lones[mt] = MFMA(pf[mt], ones,    lones[mt]);
            }
        }
        // prefetch next G
        {
            const int gstep = (it < 31) ? 128 : 0;
            gp0 += gstep; gp1 += gstep;
            #pragma unroll
            for (int k2 = 0; k2 < 4; ++k2) {
                gf0[k2] = *(const short8*)(gp0 + k2 * 32);
                gf1[k2] = *(const short8*)(gp1 + k2 * 32);
            }
        }
    }

    // ---- skip path h = fT * (w1b / SQ): same C/D layout as u (R6) ----
    floatx4 hacc[4][2];
    {
        const float RSQ = 2.8001530f;   // 1 / 0.35712442
        #pragma unroll
        for (int j = 0; j < 2; ++j) {
            int o = w * 32 + j * 16 + lm;
            short8 wf[4];
            #pragma unroll
            for (int ks = 0; ks < 4; ++ks) {
                const float* wp = w1 + (size_t)o * 256 + NC + ks * 32 + lq * 8;
                S8U t;
                t.u2[0] = make_uint2(pack2bf(wp[0] * RSQ, wp[1] * RSQ),
                                     pack2bf(wp[2] * RSQ, wp[3] * RSQ));
                t.u2[1] = make_uint2(pack2bf(wp[4] * RSQ, wp[5] * RSQ),
                                     pack2bf(wp[6] * RSQ, wp[7] * RSQ));
                wf[ks] = t.v;
            }
            #pragma unroll
            for (int mt = 0; mt < 4; ++mt) {
                floatx4 a = {0.f, 0.f, 0.f, 0.f};
                #pragma unroll
                for (int ks = 0; ks < 4; ++ks)
                    a = MFMA(qf[mt][ks], wf[ks], a);
                hacc[mt][j] = a;
            }
        }
    }

    // ---- epilogue: BN + leaky + w2 dot over this wave's 32 o (R4) ----
    float Abn[2], Dbn[2], W2[2];
    #pragma unroll
    for (int j = 0; j < 2; ++j) {
        int o = w * 32 + j * 16 + lm;
        float Ar = gammav[o] * rsqrtf(rvarv[o] + 1e-5f);
        Abn[j] = Ar;
        Dbn[j] = (b1v[o] - rmeanv[o]) * Ar + betav[o];
        W2[j]  = w2v[o];
    }
    float av[16];
    #pragma unroll
    for (int mt = 0; mt < 4; ++mt) {
        #pragma unroll
        for (int r = 0; r < 4; ++r) {
            float rl = 1.f / lones[mt][r];
            float t0 = Abn[0] * (u[mt][0][r] * rl + hacc[mt][0][r]) + Dbn[0];
            float t1 = Abn[1] * (u[mt][1][r] * rl + hacc[mt][1][r]) + Dbn[1];
            t0 = t0 >= 0.f ? t0 : 0.01f * t0;
            t1 = t1 >= 0.f ? t1 : 0.01f * t1;
            av[mt * 4 + r] = W2[0] * t0 + W2[1] * t1;
        }
    }
    #pragma unroll
    for (int i = 0; i < 16; ++i) {
        av[i] += __shfl_xor(av[i], 1);
        av[i] += __shfl_xor(av[i], 2);
        av[i] += __shfl_xor(av[i], 4);
        av[i] += __shfl_xor(av[i], 8);
    }
    if (lm == 0) {
        #pragma unroll
        for (int mt = 0; mt < 4; ++mt)
            #pragma unroll
            for (int r = 0; r < 4; ++r)
                opart[w][mt * 16 + lq * 4 + r] = av[mt * 4 + r];
    }
    __syncthreads();
    if (tid < 64)
        out[(size_t)b * NM + m0 + tid] =
            b2v[0] + opart[0][tid] + opart[1][tid] + opart[2][tid] + opart[3][tid];
}

extern "C" void kernel_launch(void* const* d_in, const int* in_sizes, int n_in,
                              void* d_out, int out_size, void* d_ws, size_t ws_size,
                              hipStream_t stream) {
    const float* f     = (const float*)d_in[0];
    const float* w1    = (const float*)d_in[1];
    const float* b1    = (const float*)d_in[2];
    const float* gamma = (const float*)d_in[3];
    const float* beta  = (const float*)d_in[4];
    const float* rmean = (const float*)d_in[5];
    const float* rvar  = (const float*)d_in[6];
    const float* w2    = (const float*)d_in[7];
    const float* b2    = (const float*)d_in[8];
    float* out = (float*)d_out;

    unsigned short* fT = (unsigned short*)d_ws;              // 8 MB bf16 [b][m][c]
    unsigned short* gN = fT + (size_t)NB * NM * NC;          // 8 MB bf16 [b][o][n]

    hipLaunchKernelGGL(prep_ft, dim3(512), dim3(256), 0, stream, f, fT);
    hipLaunchKernelGGL(prep_g,  dim3(512), dim3(256), 0, stream, f, w1, gN);
    hipLaunchKernelGGL(attn_kernel, dim3(512), dim3(256), 0, stream,
                       fT, gN, w1, b1, gamma, beta, rmean, rvar, w2, b2, out);
}

// Round 10
// 186.644 us; speedup vs baseline: 1.8357x; 1.2016x over previous
//
#include <hip/hip_runtime.h>

#define NB 8
#define NC 128
#define NM 4096

typedef __attribute__((ext_vector_type(8))) short short8;
typedef __attribute__((ext_vector_type(4))) float floatx4;

#define MFMA(a, b, c) __builtin_amdgcn_mfma_f32_16x16x32_bf16(a, b, c, 0, 0, 0)
#define EXP2F(x) __builtin_amdgcn_exp2f(x)

union S8U { short8 v; uint2 u2[2]; };

__device__ __forceinline__ unsigned pack2bf(float a, float b) {
    unsigned ua = __float_as_uint(a);
    unsigned ub = __float_as_uint(b);
    ua += 0x7fffu + ((ua >> 16) & 1u);
    ub += 0x7fffu + ((ub >> 16) & 1u);
    return (ua >> 16) | (ub & 0xffff0000u);
}

__device__ __forceinline__ void fma4(float4& a, float s, const float4& v) {
    a.x += s * v.x; a.y += s * v.y; a.z += s * v.z; a.w += s * v.w;
}

// ---------------------------------------------------------------------------
// Fragment-order layouts (one contiguous 1024B chunk per wave fragment load):
//   fK[b][mt(256)][ks(4)][lane(64)][8] : lane l=(lq*16+lm) holds
//       f-row (mt*16+lm), cols ks*32+lq*8..+7, scaled by SQ, bf16.
//   gK[b][nblk(32)][ot(8)][k2(4)][lane(64)][8] : lane l holds
//       g-row o=ot*16+lm, cols n=nblk*128+k2*32+lq*8..+7, bf16.
// ---------------------------------------------------------------------------

// P1: fK from f (transpose + scale + bf16 + fragment order)
__global__ __launch_bounds__(256) void prep_ft(
    const float* __restrict__ f, unsigned short* __restrict__ fK)
{
    __shared__ float Ls[128][65];
    const int tid = threadIdx.x;
    const int b   = blockIdx.x & 7;
    const int m0  = (blockIdx.x >> 3) << 6;
    const float* fb = f + (size_t)b * NC * NM;
    #pragma unroll
    for (int k = 0; k < 32; ++k) {
        int idx = tid + (k << 8);
        int c = idx >> 6, mm = idx & 63;
        Ls[c][mm] = fb[(size_t)c * NM + m0 + mm];
    }
    __syncthreads();
    const float SQ = 0.35712442f;   // sqrt(2^-3.5 * log2(e))
    const int m  = tid >> 2;        // 0..63 (row within block)
    const int ks = tid & 3;
    const int ch = ks << 5;
    unsigned pk[16];
    #pragma unroll
    for (int i = 0; i < 16; ++i)
        pk[i] = pack2bf(Ls[ch + 2 * i][m] * SQ, Ls[ch + 2 * i + 1][m] * SQ);
    const int Mg = m0 + m;
    const int nt = Mg >> 4, lmm = Mg & 15;
    unsigned short* dst = fK + ((((size_t)b * 256 + nt) * 4 + ks) << 9);
    #pragma unroll
    for (int lqq = 0; lqq < 4; ++lqq)
        *(uint4*)(dst + (lqq * 16 + lmm) * 8) =
            make_uint4(pk[4 * lqq], pk[4 * lqq + 1], pk[4 * lqq + 2], pk[4 * lqq + 3]);
}

// P2: gK = bf16( w1a . f ) in fragment order.
// grid 256 = b(8) x nt4(4: 1024 n) x ot(8: 16 o); 256 thr, 4 n x 16 o each.
__global__ __launch_bounds__(256) void prep_g(
    const float* __restrict__ f, const float* __restrict__ w1,
    unsigned short* __restrict__ gK)
{
    __shared__ float Ws[128][16];
    const int tid = threadIdx.x;
    const int b   = blockIdx.x & 7;
    const int nt4 = (blockIdx.x >> 3) & 3;
    const int ot  = blockIdx.x >> 5;         // 0..7
    const int o0  = ot << 4;
    for (int i = tid; i < 128 * 16; i += 256) {
        int c = i >> 4, k = i & 15;
        Ws[c][k] = w1[(o0 + k) * 256 + c];
    }
    __syncthreads();

    const int ng = (nt4 << 10) + (tid << 2);        // global n of this thread
    const float* fb = f + (size_t)b * NC * NM + ng;
    float4 acc[16];
    #pragma unroll
    for (int j = 0; j < 16; ++j) acc[j] = make_float4(0.f, 0.f, 0.f, 0.f);

    for (int c = 0; c < NC; ++c) {
        float4 fv = *(const float4*)(fb + (size_t)c * NM);
        const float4* wq = (const float4*)&Ws[c][0];
        float4 w0 = wq[0], w1q = wq[1], w2q = wq[2], w3q = wq[3];
        fma4(acc[0],  w0.x,  fv); fma4(acc[1],  w0.y,  fv);
        fma4(acc[2],  w0.z,  fv); fma4(acc[3],  w0.w,  fv);
        fma4(acc[4],  w1q.x, fv); fma4(acc[5],  w1q.y, fv);
        fma4(acc[6],  w1q.z, fv); fma4(acc[7],  w1q.w, fv);
        fma4(acc[8],  w2q.x, fv); fma4(acc[9],  w2q.y, fv);
        fma4(acc[10], w2q.z, fv); fma4(acc[11], w2q.w, fv);
        fma4(acc[12], w3q.x, fv); fma4(acc[13], w3q.y, fv);
        fma4(acc[14], w3q.z, fv); fma4(acc[15], w3q.w, fv);
    }

    const int nblk = ng >> 7;
    const int nn   = ng & 127;
    const int k2   = nn >> 5, lqq = (nn >> 3) & 3, e0 = nn & 7;   // e0 in {0,4}
    unsigned short* base = gK +
        ((((size_t)b * 32 + nblk) * 8 + ot) * 4 + k2) * 512 + lqq * 128 + e0;
    #pragma unroll
    for (int j = 0; j < 16; ++j) {
        unsigned lo = pack2bf(acc[j].x, acc[j].y);
        unsigned hi = pack2bf(acc[j].z, acc[j].w);
        *(uint2*)(base + j * 8) = make_uint2(lo, hi);
    }
}

// ---------------------------------------------------------------------------
// Main: MFMA flash attention + fused cls head, TN=128/iter, fragment-order
// K/G loads (1 contiguous 1024B chunk per wave per fragment -> 8x fewer L1
// requests than the R9 row-scatter).  Structure otherwise identical to R9.
// grid 512 = b(8) x mblock(64, 64 m); 256 thr = 4 waves, 2 blocks/CU.
// ---------------------------------------------------------------------------
__global__ __launch_bounds__(256, 2) void attn_kernel(
    const unsigned short* __restrict__ fK,
    const unsigned short* __restrict__ gK,
    const float* __restrict__ w1,
    const float* __restrict__ b1v, const float* __restrict__ gammav,
    const float* __restrict__ betav, const float* __restrict__ rmeanv,
    const float* __restrict__ rvarv, const float* __restrict__ w2v,
    const float* __restrict__ b2v, float* __restrict__ out)
{
    __shared__ unsigned short Ps[2][64][136];   // [buf][m][n] bf16 P-hat
    __shared__ float opart[4][64];

    const int tid = threadIdx.x;
    const int w   = tid >> 6;
    const int l   = tid & 63;
    const int lm  = l & 15;
    const int lq  = l >> 4;
    const int b   = blockIdx.x & 7;
    const int m0  = (blockIdx.x >> 3) << 6;

    const unsigned short* fKb = fK + (size_t)b * NM * NC;
    const unsigned short* gKb = gK + (size_t)b * NC * NM;

    // stationary Q frags (fragment-order: one contiguous load each)
    short8 qf[4][4];
    {
        const int qt0 = m0 >> 4;
        #pragma unroll
        for (int mt = 0; mt < 4; ++mt)
            #pragma unroll
            for (int ks = 0; ks < 4; ++ks)
                qf[mt][ks] = *(const short8*)
                    (fKb + ((((qt0 + mt) * 4 + ks)) << 9) + l * 8);
    }

    short8 ones;
    #pragma unroll
    for (int j = 0; j < 8; ++j) ones[j] = (short)0x3F80;   // bf16 1.0

    // K tiles per iter: A = 8*it + w, B = 8*it + 4 + w
    const unsigned short* kpA = fKb + ((w * 4) << 9) + l * 8;
    const unsigned short* kpB = fKb + (((4 + w) * 4) << 9) + l * 8;
    // G tiles per iter: nblk = it, ot = 2w (gf0) / 2w+1 (gf1)
    const unsigned short* gp0 = gKb + (((2 * w) * 4) << 9) + l * 8;
    const unsigned short* gp1 = gKb + (((2 * w + 1) * 4) << 9) + l * 8;

    short8 kfA[4], kfB[4], gf0[4], gf1[4];
    #pragma unroll
    for (int ks = 0; ks < 4; ++ks) {
        kfA[ks] = *(const short8*)(kpA + (ks << 9));
        kfB[ks] = *(const short8*)(kpB + (ks << 9));
    }
    #pragma unroll
    for (int k2 = 0; k2 < 4; ++k2) {
        gf0[k2] = *(const short8*)(gp0 + (k2 << 9));
        gf1[k2] = *(const short8*)(gp1 + (k2 << 9));
    }

    floatx4 u[4][2], lones[4];
    #pragma unroll
    for (int mt = 0; mt < 4; ++mt) {
        u[mt][0] = (floatx4){0.f, 0.f, 0.f, 0.f};
        u[mt][1] = (floatx4){0.f, 0.f, 0.f, 0.f};
        lones[mt] = (floatx4){0.f, 0.f, 0.f, 0.f};
    }

    for (int it = 0; it < 32; ++it) {
        const int buf = it & 1;

        // ---- S^T = K * Q^T (two 16-n tiles), acc seeded -24 ----
        floatx4 svA[4], svB[4];
        #pragma unroll
        for (int mt = 0; mt < 4; ++mt) {
            floatx4 a = {-24.f, -24.f, -24.f, -24.f};
            floatx4 bb = {-24.f, -24.f, -24.f, -24.f};
            #pragma unroll
            for (int ks = 0; ks < 4; ++ks) {
                a  = MFMA(kfA[ks], qf[mt][ks], a);
                bb = MFMA(kfB[ks], qf[mt][ks], bb);
            }
            svA[mt] = a; svB[mt] = bb;
        }
        // prefetch next K (8 tiles = 16384 shorts per iter)
        {
            const int kstep = (it < 31) ? 16384 : 0;
            kpA += kstep; kpB += kstep;
            #pragma unroll
            for (int ks = 0; ks < 4; ++ks) {
                kfA[ks] = *(const short8*)(kpA + (ks << 9));
                kfB[ks] = *(const short8*)(kpB + (ks << 9));
            }
        }

        // ---- p-hat = bf16(exp2(s)) -> LDS P tile ----
        #pragma unroll
        for (int mt = 0; mt < 4; ++mt) {
            *(uint2*)&Ps[buf][mt * 16 + lm][w * 16 + lq * 4] =
                make_uint2(pack2bf(EXP2F(svA[mt][0]), EXP2F(svA[mt][1])),
                           pack2bf(EXP2F(svA[mt][2]), EXP2F(svA[mt][3])));
            *(uint2*)&Ps[buf][mt * 16 + lm][64 + w * 16 + lq * 4] =
                make_uint2(pack2bf(EXP2F(svB[mt][0]), EXP2F(svB[mt][1])),
                           pack2bf(EXP2F(svB[mt][2]), EXP2F(svB[mt][3])));
        }
        __syncthreads();

        // ---- PV + l over the 128-n tile ----
        #pragma unroll
        for (int k2 = 0; k2 < 4; ++k2) {
            short8 pf[4];
            #pragma unroll
            for (int mt = 0; mt < 4; ++mt)
                pf[mt] = *(const short8*)&Ps[buf][mt * 16 + lm][k2 * 32 + lq * 8];
            #pragma unroll
            for (int mt = 0; mt < 4; ++mt) {
                u[mt][0]  = MFMA(pf[mt], gf0[k2], u[mt][0]);
                u[mt][1]  = MFMA(pf[mt], gf1[k2], u[mt][1]);
                lones[mt] = MFMA(pf[mt], ones,    lones[mt]);
            }
        }
        // prefetch next G (one nblk = 16384 shorts per iter)
        {
            const int gstep = (it < 31) ? 16384 : 0;
            gp0 += gstep; gp1 += gstep;
            #pragma unroll
            for (int k2 = 0; k2 < 4; ++k2) {
                gf0[k2] = *(const short8*)(gp0 + (k2 << 9));
                gf1[k2] = *(const short8*)(gp1 + (k2 << 9));
            }
        }
    }

    // ---- skip path h = fT * (w1b / SQ): same C/D layout as u ----
    floatx4 hacc[4][2];
    {
        const float RSQ = 2.8001530f;   // 1 / 0.35712442
        #pragma unroll
        for (int j = 0; j < 2; ++j) {
            int o = w * 32 + j * 16 + lm;
            short8 wf[4];
            #pragma unroll
            for (int ks = 0; ks < 4; ++ks) {
                const float* wp = w1 + (size_t)o * 256 + NC + ks * 32 + lq * 8;
                S8U t;
                t.u2[0] = make_uint2(pack2bf(wp[0] * RSQ, wp[1] * RSQ),
                                     pack2bf(wp[2] * RSQ, wp[3] * RSQ));
                t.u2[1] = make_uint2(pack2bf(wp[4] * RSQ, wp[5] * RSQ),
                                     pack2bf(wp[6] * RSQ, wp[7] * RSQ));
                wf[ks] = t.v;
            }
            #pragma unroll
            for (int mt = 0; mt < 4; ++mt) {
                floatx4 a = {0.f, 0.f, 0.f, 0.f};
                #pragma unroll
                for (int ks = 0; ks < 4; ++ks)
                    a = MFMA(qf[mt][ks], wf[ks], a);
                hacc[mt][j] = a;
            }
        }
    }

    // ---- epilogue: BN + leaky + w2 dot over this wave's 32 o ----
    float Abn[2], Dbn[2], W2[2];
    #pragma unroll
    for (int j = 0; j < 2; ++j) {
        int o = w * 32 + j * 16 + lm;
        float Ar = gammav[o] * rsqrtf(rvarv[o] + 1e-5f);
        Abn[j] = Ar;
        Dbn[j] = (b1v[o] - rmeanv[o]) * Ar + betav[o];
        W2[j]  = w2v[o];
    }
    float av[16];
    #pragma unroll
    for (int mt = 0; mt < 4; ++mt) {
        #pragma unroll
        for (int r = 0; r < 4; ++r) {
            float rl = 1.f / lones[mt][r];
            float t0 = Abn[0] * (u[mt][0][r] * rl + hacc[mt][0][r]) + Dbn[0];
            float t1 = Abn[1] * (u[mt][1][r] * rl + hacc[mt][1][r]) + Dbn[1];
            t0 = t0 >= 0.f ? t0 : 0.01f * t0;
            t1 = t1 >= 0.f ? t1 : 0.01f * t1;
            av[mt * 4 + r] = W2[0] * t0 + W2[1] * t1;
        }
    }
    #pragma unroll
    for (int i = 0; i < 16; ++i) {
        av[i] += __shfl_xor(av[i], 1);
        av[i] += __shfl_xor(av[i], 2);
        av[i] += __shfl_xor(av[i], 4);
        av[i] += __shfl_xor(av[i], 8);
    }
    if (lm == 0) {
        #pragma unroll
        for (int mt = 0; mt < 4; ++mt)
            #pragma unroll
            for (int r = 0; r < 4; ++r)
                opart[w][mt * 16 + lq * 4 + r] = av[mt * 4 + r];
    }
    __syncthreads();
    if (tid < 64)
        out[(size_t)b * NM + m0 + tid] =
            b2v[0] + opart[0][tid] + opart[1][tid] + opart[2][tid] + opart[3][tid];
}

extern "C" void kernel_launch(void* const* d_in, const int* in_sizes, int n_in,
                              void* d_out, int out_size, void* d_ws, size_t ws_size,
                              hipStream_t stream) {
    const float* f     = (const float*)d_in[0];
    const float* w1    = (const float*)d_in[1];
    const float* b1    = (const float*)d_in[2];
    const float* gamma = (const float*)d_in[3];
    const float* beta  = (const float*)d_in[4];
    const float* rmean = (const float*)d_in[5];
    const float* rvar  = (const float*)d_in[6];
    const float* w2    = (const float*)d_in[7];
    const float* b2    = (const float*)d_in[8];
    float* out = (float*)d_out;

    unsigned short* fK = (unsigned short*)d_ws;              // 8 MB bf16 frag-order
    unsigned short* gK = fK + (size_t)NB * NM * NC;          // 8 MB bf16 frag-order

    hipLaunchKernelGGL(prep_ft, dim3(512), dim3(256), 0, stream, f, fK);
    hipLaunchKernelGGL(prep_g,  dim3(256), dim3(256), 0, stream, f, w1, gK);
    hipLaunchKernelGGL(attn_kernel, dim3(512), dim3(256), 0, stream,
                       fK, gK, w1, b1, gamma, beta, rmean, rvar, w2, b2, out);
}

// Round 14
// 162.179 us; speedup vs baseline: 2.1126x; 1.1509x over previous
//
#include <hip/hip_runtime.h>

#define NB 8
#define NC 128
#define NM 4096
#define FRAG 512   // shorts per (tile,ks) fragment block: 64 lanes x 8

typedef __attribute__((ext_vector_type(8))) short short8;
typedef __attribute__((ext_vector_type(4))) float floatx4;

#define MFMA(a, b, c) __builtin_amdgcn_mfma_f32_16x16x32_bf16(a, b, c, 0, 0, 0)
#define EXP2F(x) __builtin_amdgcn_exp2f(x)

union S8U { short8 v; uint2 u2[2]; };

__device__ __forceinline__ unsigned pack2bf(float a, float b) {
    unsigned ua = __float_as_uint(a);
    unsigned ub = __float_as_uint(b);
    ua += 0x7fffu + ((ua >> 16) & 1u);
    ub += 0x7fffu + ((ub >> 16) & 1u);
    return (ua >> 16) | (ub & 0xffff0000u);
}

// QK softmax scale folded into fX: sqrt(2^-3.5 * log2(e)); RS = 1/SF.
__constant__ float SF_C = 0.35712442f;
__constant__ float RS_C = 2.8001530f;

// ---------------------------------------------------------------------------
// Fragment-order layouts (one contiguous 1024B chunk per wave fragment load):
//   fX[b][mt(256)][ks(4)][lane(64)][8] : lane l=(lq*16+lm) holds
//       f-row (mt*16+lm), cols ks*32+lq*8..+7, scaled by SF, bf16.
//   gX[b][nblk(32)][ot(8)][k2(4)][lane(64)][8] : lane l holds
//       g-row o=ot*16+lm, cols n=nblk*128+k2*32+lq*8..+7, bf16.
// ---------------------------------------------------------------------------

// P1: fX from f (transpose + scale + bf16 + fragment order)
__global__ __launch_bounds__(256) void k_prep_f(
    const float* __restrict__ f, unsigned short* __restrict__ fX)
{
    __shared__ float Ls[128][65];
    const int tid = threadIdx.x;
    const int b   = blockIdx.x & 7;
    const int m0  = (blockIdx.x >> 3) * 64;
    const float* fb = f + (size_t)b * NC * NM;
    #pragma unroll
    for (int k = 0; k < 32; ++k) {
        int idx = tid + k * 256;
        int c = idx >> 6, mm = idx & 63;
        Ls[c][mm] = fb[(size_t)c * NM + m0 + mm];
    }
    __syncthreads();
    const float sf = SF_C;
    const int m  = tid >> 2;
    const int ks = tid & 3;
    const int ch = ks * 32;
    unsigned pk[16];
    #pragma unroll
    for (int i = 0; i < 16; ++i)
        pk[i] = pack2bf(Ls[ch + 2 * i][m] * sf, Ls[ch + 2 * i + 1][m] * sf);
    const int Mg  = m0 + m;
    const int mt  = Mg >> 4;
    const int lmm = Mg & 15;
    unsigned short* dst = fX + ((size_t)b * 256 + mt) * 4 * FRAG + ks * FRAG;
    #pragma unroll
    for (int q = 0; q < 4; ++q)
        *(uint4*)(dst + (q * 16 + lmm) * 8) =
            make_uint4(pk[4 * q], pk[4 * q + 1], pk[4 * q + 2], pk[4 * q + 3]);
}

// ---------------------------------------------------------------------------
// P2 (MFMA): gX = bf16( (w1a*RS) . fX ) in fragment order.
// grid 256 = b(8) x nblk(32); 4 waves; wave wv owns ot = 2wv, 2wv+1.
// ---------------------------------------------------------------------------
__global__ __launch_bounds__(256) void k_prep_g(
    const unsigned short* __restrict__ fX, const float* __restrict__ w1,
    unsigned short* __restrict__ gX)
{
    __shared__ unsigned short gt[128][136];   // [o][n-local]
    const int tid = threadIdx.x;
    const int wv  = tid >> 6;
    const int l   = tid & 63;
    const int lm  = l & 15;
    const int lq  = l >> 4;
    const int b    = blockIdx.x & 7;
    const int nblk = blockIdx.x >> 3;

    const float rs = RS_C;

    short8 wf2[2][4];
    #pragma unroll
    for (int j = 0; j < 2; ++j) {
        const int o = (wv * 2 + j) * 16 + lm;
        #pragma unroll
        for (int ks = 0; ks < 4; ++ks) {
            const float* wp = w1 + (size_t)o * (2 * NC) + ks * 32 + lq * 8;
            S8U t;
            t.u2[0] = make_uint2(pack2bf(wp[0] * rs, wp[1] * rs),
                                 pack2bf(wp[2] * rs, wp[3] * rs));
            t.u2[1] = make_uint2(pack2bf(wp[4] * rs, wp[5] * rs),
                                 pack2bf(wp[6] * rs, wp[7] * rs));
            wf2[j][ks] = t.v;
        }
    }

    const unsigned short* fXb = fX + (size_t)b * NM * NC;
    #pragma unroll 2
    for (int nt = 0; nt < 8; ++nt) {
        short8 af[4];
        #pragma unroll
        for (int ks = 0; ks < 4; ++ks)
            af[ks] = *(const short8*)
                (fXb + (size_t)(nblk * 8 + nt) * 4 * FRAG + ks * FRAG + l * 8);
        #pragma unroll
        for (int j = 0; j < 2; ++j) {
            floatx4 D = {0.f, 0.f, 0.f, 0.f};
            #pragma unroll
            for (int ks = 0; ks < 4; ++ks)
                D = MFMA(af[ks], wf2[j][ks], D);
            *(uint2*)&gt[(wv * 2 + j) * 16 + lm][nt * 16 + lq * 4] =
                make_uint2(pack2bf(D[0], D[1]), pack2bf(D[2], D[3]));
        }
    }
    __syncthreads();

    #pragma unroll
    for (int j = 0; j < 2; ++j) {
        const int ot = wv * 2 + j;
        #pragma unroll
        for (int k2 = 0; k2 < 4; ++k2) {
            uint4 v = *(const uint4*)&gt[ot * 16 + lm][k2 * 32 + lq * 8];
            *(uint4*)(gX + (((size_t)b * 32 + nblk) * 8 + ot) * 4 * FRAG
                      + k2 * FRAG + l * 8) = v;
        }
    }
}

// ---------------------------------------------------------------------------
// Main: MFMA flash attention + fused cls head, TN=128/iter, fragment-order
// K/G loads; l in fp32 VALU from the exp2 registers feeding Ps.
// grid 512 = b(8) x mblock(64, 64 m); 4 waves, 2 blocks/CU.
// ---------------------------------------------------------------------------
__global__ __launch_bounds__(256, 2) void k_attn(
    const unsigned short* __restrict__ fX,
    const unsigned short* __restrict__ gX,
    const float* __restrict__ w1,
    const float* __restrict__ b1v, const float* __restrict__ gammav,
    const float* __restrict__ betav, const float* __restrict__ rmeanv,
    const float* __restrict__ rvarv, const float* __restrict__ w2v,
    const float* __restrict__ b2v, float* __restrict__ out)
{
    __shared__ unsigned short Ps[2][64][136];
    __shared__ float lpart[4][64];
    __shared__ float opart[4][64];

    const int tid = threadIdx.x;
    const int w   = tid >> 6;
    const int l   = tid & 63;
    const int lm  = l & 15;
    const int lq  = l >> 4;
    const int b   = blockIdx.x & 7;
    const int m0  = (blockIdx.x >> 3) * 64;

    const unsigned short* fXb = fX + (size_t)b * NM * NC;
    const unsigned short* gXb = gX + (size_t)b * NC * NM;

    short8 qf[4][4];
    {
        const int qt0 = m0 >> 4;
        #pragma unroll
        for (int mt = 0; mt < 4; ++mt)
            #pragma unroll
            for (int ks = 0; ks < 4; ++ks)
                qf[mt][ks] = *(const short8*)
                    (fXb + (size_t)(qt0 + mt) * 4 * FRAG + ks * FRAG + l * 8);
    }

    const unsigned short* kpA = fXb + (size_t)w * 4 * FRAG + l * 8;
    const unsigned short* kpB = fXb + (size_t)(4 + w) * 4 * FRAG + l * 8;
    const unsigned short* gp0 = gXb + (size_t)(2 * w) * 4 * FRAG + l * 8;
    const unsigned short* gp1 = gXb + (size_t)(2 * w + 1) * 4 * FRAG + l * 8;

    short8 kfA[4], kfB[4], gf0[4], gf1[4];
    #pragma unroll
    for (int ks = 0; ks < 4; ++ks) {
        kfA[ks] = *(const short8*)(kpA + ks * FRAG);
        kfB[ks] = *(const short8*)(kpB + ks * FRAG);
    }
    #pragma unroll
    for (int k2 = 0; k2 < 4; ++k2) {
        gf0[k2] = *(const short8*)(gp0 + k2 * FRAG);
        gf1[k2] = *(const short8*)(gp1 + k2 * FRAG);
    }

    floatx4 u[4][2];
    float lsum[4] = {0.f, 0.f, 0.f, 0.f};
    #pragma unroll
    for (int mt = 0; mt < 4; ++mt) {
        u[mt][0] = (floatx4){0.f, 0.f, 0.f, 0.f};
        u[mt][1] = (floatx4){0.f, 0.f, 0.f, 0.f};
    }

    for (int it = 0; it < 32; ++it) {
        const int buf = it & 1;

        floatx4 svA[4], svB[4];
        #pragma unroll
        for (int mt = 0; mt < 4; ++mt) {
            floatx4 a = {-24.f, -24.f, -24.f, -24.f};
            floatx4 bb = {-24.f, -24.f, -24.f, -24.f};
            #pragma unroll
            for (int ks = 0; ks < 4; ++ks) {
                a  = MFMA(kfA[ks], qf[mt][ks], a);
                bb = MFMA(kfB[ks], qf[mt][ks], bb);
            }
            svA[mt] = a; svB[mt] = bb;
        }
        {
            const int kstep = (it < 31) ? 8 * 4 * FRAG : 0;
            kpA += kstep; kpB += kstep;
            #pragma unroll
            for (int ks = 0; ks < 4; ++ks) {
                kfA[ks] = *(const short8*)(kpA + ks * FRAG);
                kfB[ks] = *(const short8*)(kpB + ks * FRAG);
            }
        }

        #pragma unroll
        for (int mt = 0; mt < 4; ++mt) {
            float pA0 = EXP2F(svA[mt][0]);
            float pA1 = EXP2F(svA[mt][1]);
            float pA2 = EXP2F(svA[mt][2]);
            float pA3 = EXP2F(svA[mt][3]);
            float pB0 = EXP2F(svB[mt][0]);
            float pB1 = EXP2F(svB[mt][1]);
            float pB2 = EXP2F(svB[mt][2]);
            float pB3 = EXP2F(svB[mt][3]);
            lsum[mt] += ((pA0 + pA1) + (pA2 + pA3)) +
                        ((pB0 + pB1) + (pB2 + pB3));
            *(uint2*)&Ps[buf][mt * 16 + lm][w * 16 + lq * 4] =
                make_uint2(pack2bf(pA0, pA1), pack2bf(pA2, pA3));
            *(uint2*)&Ps[buf][mt * 16 + lm][64 + w * 16 + lq * 4] =
                make_uint2(pack2bf(pB0, pB1), pack2bf(pB2, pB3));
        }
        __syncthreads();

        #pragma unroll
        for (int k2 = 0; k2 < 4; ++k2) {
            short8 pf[4];
            #pragma unroll
            for (int mt = 0; mt < 4; ++mt)
                pf[mt] = *(const short8*)&Ps[buf][mt * 16 + lm][k2 * 32 + lq * 8];
            #pragma unroll
            for (int mt = 0; mt < 4; ++mt) {
                u[mt][0] = MFMA(pf[mt], gf0[k2], u[mt][0]);
                u[mt][1] = MFMA(pf[mt], gf1[k2], u[mt][1]);
            }
        }
        {
            const int gstep = (it < 31) ? 8 * 4 * FRAG : 0;
            gp0 += gstep; gp1 += gstep;
            #pragma unroll
            for (int k2 = 0; k2 < 4; ++k2) {
                gf0[k2] = *(const short8*)(gp0 + k2 * FRAG);
                gf1[k2] = *(const short8*)(gp1 + k2 * FRAG);
            }
        }
    }

    #pragma unroll
    for (int mt = 0; mt < 4; ++mt) {
        lsum[mt] += __shfl_xor(lsum[mt], 16);
        lsum[mt] += __shfl_xor(lsum[mt], 32);
    }
    if (lq == 0) {
        #pragma unroll
        for (int mt = 0; mt < 4; ++mt)
            lpart[w][mt * 16 + lm] = lsum[mt];
    }

    floatx4 hacc[4][2];
    {
        const float rs = RS_C;
        #pragma unroll
        for (int j = 0; j < 2; ++j) {
            int o = w * 32 + j * 16 + lm;
            short8 wf[4];
            #pragma unroll
            for (int ks = 0; ks < 4; ++ks) {
                const float* wp = w1 + (size_t)o * (2 * NC) + NC + ks * 32 + lq * 8;
                S8U t;
                t.u2[0] = make_uint2(pack2bf(wp[0] * rs, wp[1] * rs),
                                     pack2bf(wp[2] * rs, wp[3] * rs));
                t.u2[1] = make_uint2(pack2bf(wp[4] * rs, wp[5] * rs),
                                     pack2bf(wp[6] * rs, wp[7] * rs));
                wf[ks] = t.v;
            }
            #pragma unroll
            for (int mt = 0; mt < 4; ++mt) {
                floatx4 a = {0.f, 0.f, 0.f, 0.f};
                #pragma unroll
                for (int ks = 0; ks < 4; ++ks)
                    a = MFMA(qf[mt][ks], wf[ks], a);
                hacc[mt][j] = a;
            }
        }
    }
    __syncthreads();

    float Abn[2], Dbn[2], W2[2];
    #pragma unroll
    for (int j = 0; j < 2; ++j) {
        int o = w * 32 + j * 16 + lm;
        float Ar = gammav[o] * rsqrtf(rvarv[o] + 1e-5f);
        Abn[j] = Ar;
        Dbn[j] = (b1v[o] - rmeanv[o]) * Ar + betav[o];
        W2[j]  = w2v[o];
    }
    float av[16];
    #pragma unroll
    for (int mt = 0; mt < 4; ++mt) {
        float4 L0 = *(const float4*)&lpart[0][mt * 16 + lq * 4];
        float4 L1 = *(const float4*)&lpart[1][mt * 16 + lq * 4];
        float4 L2 = *(const float4*)&lpart[2][mt * 16 + lq * 4];
        float4 L3 = *(const float4*)&lpart[3][mt * 16 + lq * 4];
        float4 Lt;
        Lt.x = (L0.x + L1.x) + (L2.x + L3.x);
        Lt.y = (L0.y + L1.y) + (L2.y + L3.y);
        Lt.z = (L0.z + L1.z) + (L2.z + L3.z);
        Lt.w = (L0.w + L1.w) + (L2.w + L3.w);
        #pragma unroll
        for (int r = 0; r < 4; ++r) {
            float rl = 1.f / ((const float*)&Lt)[r];
            float t0 = Abn[0] * (u[mt][0][r] * rl + hacc[mt][0][r]) + Dbn[0];
            float t1 = Abn[1] * (u[mt][1][r] * rl + hacc[mt][1][r]) + Dbn[1];
            t0 = t0 >= 0.f ? t0 : 0.01f * t0;
            t1 = t1 >= 0.f ? t1 : 0.01f * t1;
            av[mt * 4 + r] = W2[0] * t0 + W2[1] * t1;
        }
    }
    #pragma unroll
    for (int i = 0; i < 16; ++i) {
        av[i] += __shfl_xor(av[i], 1);
        av[i] += __shfl_xor(av[i], 2);
        av[i] += __shfl_xor(av[i], 4);
        av[i] += __shfl_xor(av[i], 8);
    }
    if (lm == 0) {
        #pragma unroll
        for (int mt = 0; mt < 4; ++mt)
            #pragma unroll
            for (int r = 0; r < 4; ++r)
                opart[w][mt * 16 + lq * 4 + r] = av[mt * 4 + r];
    }
    __syncthreads();
    if (tid < 64)
        out[(size_t)b * NM + m0 + tid] =
            b2v[0] + opart[0][tid] + opart[1][tid] + opart[2][tid] + opart[3][tid];
}

extern "C" void kernel_launch(void* const* d_in, const int* in_sizes, int n_in,
                              void* d_out, int out_size, void* d_ws, size_t ws_size,
                              hipStream_t stream) {
    const float* f     = (const float*)d_in[0];
    const float* w1    = (const float*)d_in[1];
    const float* b1    = (const float*)d_in[2];
    const float* gamma = (const float*)d_in[3];
    const float* beta  = (const float*)d_in[4];
    const float* rmean = (const float*)d_in[5];
    const float* rvar  = (const float*)d_in[6];
    const float* w2    = (const float*)d_in[7];
    const float* b2    = (const float*)d_in[8];
    float* out = (float*)d_out;

    unsigned short* fX = (unsigned short*)d_ws;              // 8 MB bf16 frag-order
    unsigned short* gX = fX + (size_t)NB * NM * NC;          // 8 MB bf16 frag-order

    hipLaunchKernelGGL(k_prep_f, dim3(512), dim3(256), 0, stream, f, fX);
    hipLaunchKernelGGL(k_prep_g, dim3(256), dim3(256), 0, stream, fX, w1, gX);
    hipLaunchKernelGGL(k_attn,   dim3(512), dim3(256), 0, stream,
                       fX, gX, w1, b1, gamma, beta, rmean, rvar, w2, b2, out);
}